// Round 1
// baseline (623.524 us; speedup 1.0000x reference)
//
#include <hip/hip_runtime.h>
#include <hip/hip_bf16.h>

#define E 8
#define D 2048
#define H 8192
#define R 64
#define NTOK 4096

#define TILE_M 32
#define KC 128
#define PK 136   // pitch (bf16 elems) for 128-deep k tiles: 272B rows, 16B aligned
#define PR 72    // pitch for 64-deep k tiles: 144B rows, 16B aligned

typedef __attribute__((ext_vector_type(8))) short bf16x8;
typedef __attribute__((ext_vector_type(4))) float f32x4;

__device__ __forceinline__ unsigned short f2b(float f){
  union { __hip_bfloat16 h; unsigned short u; } cv;
  cv.h = __float2bfloat16(f);
  return cv.u;
}

// A- and B-fragment for mfma_f32_16x16x32_bf16 from a [row][k]-major LDS tile:
// lane l reads row0+(l&15), k = k0 + (l>>4)*8 .. +7  (16B contiguous -> ds_read_b128)
__device__ __forceinline__ bf16x8 ldfrag(const unsigned short* base, int row0, int k0,
                                         int pitch, int lane){
  return *reinterpret_cast<const bf16x8*>(base + (row0 + (lane & 15)) * pitch
                                          + k0 + ((lane >> 4) << 3));
}

// ---------------- gate: f32 logits, top-2, renorm, build expert lists ----------------
__global__ __launch_bounds__(256) void gate_kernel(
    const float* __restrict__ x, const float* __restrict__ gw,
    const float* __restrict__ gb, int* __restrict__ cnt,
    int* __restrict__ lst, float* __restrict__ wl)
{
  int wid  = threadIdx.x >> 6;
  int lane = threadIdx.x & 63;
  int n = blockIdx.x * 4 + wid;
  if (n >= NTOK) return;

  const float* xr = x + (size_t)n * D;
  float acc[E];
  #pragma unroll
  for (int e = 0; e < E; ++e) acc[e] = 0.f;

  for (int i = 0; i < D / 64; ++i){
    int d = i * 64 + lane;
    float xv = xr[d];
    #pragma unroll
    for (int e = 0; e < E; ++e) acc[e] += xv * gw[e * D + d];
  }
  #pragma unroll
  for (int e = 0; e < E; ++e){
    float v = acc[e];
    for (int off = 32; off; off >>= 1) v += __shfl_xor(v, off, 64);
    acc[e] = v + gb[e];
  }
  if (lane == 0){
    float l0 = -1e30f, l1 = -1e30f; int i0 = 0, i1 = 0;
    #pragma unroll
    for (int e = 0; e < E; ++e){
      float v = acc[e];
      if (v > l0){ l1 = l0; i1 = i0; l0 = v; i0 = e; }
      else if (v > l1){ l1 = v; i1 = e; }
    }
    float t  = expf(l1 - l0);      // <= 1
    float w0 = 1.f / (1.f + t);    // = p0/(p0+p1) exactly
    float w1 = t * w0;
    int p0 = atomicAdd(&cnt[i0], 1);
    lst[i0 * NTOK + p0] = n;  wl[i0 * NTOK + p0] = w0;
    int p1 = atomicAdd(&cnt[i1], 1);
    lst[i1 * NTOK + p1] = n;  wl[i1 * NTOK + p1] = w1;
  }
}

// ---------------- fused expert chain: per (expert, 32-token tile) ----------------
__global__ __launch_bounds__(512) void expert_kernel(
    const float* __restrict__ x,  const float* __restrict__ u1,
    const float* __restrict__ v1, const float* __restrict__ b1,
    const float* __restrict__ u2, const float* __restrict__ v2,
    const float* __restrict__ b2, const int* __restrict__ cnt,
    const int* __restrict__ lst,  const float* __restrict__ wl,
    float* __restrict__ out)
{
  int e  = blockIdx.y;
  int nc = cnt[e];
  int t0 = blockIdx.x * TILE_M;
  if (t0 >= nc) return;

  __shared__ int   s_tok[TILE_M];
  __shared__ float s_wt[TILE_M];
  __shared__ unsigned short T1s[TILE_M * PR];
  __shared__ unsigned short T2s[TILE_M * PR];
  // scratch union: phase A: Xs[32][PK] + U1T[64][PK]            = 13056 elems
  //                phase B: V1T[128][PR] + U2T[64][PK] + Hs[32][PK] = 22272 elems
  //                phase C: V2T[128][PR]                         =  9216 elems
  __shared__ unsigned short scr[22272];

  unsigned short* V1T = scr;                        // [128][PR]
  unsigned short* U2T = scr + 128 * PR;             // [64][PK]
  unsigned short* Hs  = scr + 128 * PR + 64 * PK;   // [TILE_M][PK]
  unsigned short* Xs  = scr;                        // [TILE_M][PK]
  unsigned short* U1T = scr + TILE_M * PK;          // [64][PK]
  unsigned short* V2T = scr;                        // [128][PR]

  int tid  = threadIdx.x;
  int w    = tid >> 6;
  int lane = tid & 63;

  if (tid < TILE_M){
    int i = t0 + tid;
    if (i < nc){ s_tok[tid] = lst[e * NTOK + i]; s_wt[tid] = wl[e * NTOK + i]; }
    else       { s_tok[tid] = 0;                 s_wt[tid] = 0.f; }
  }
  __syncthreads();

  // wave -> tile maps:
  //  A / B2 / T2 :  (mA, nA) = ((w>>2)*16, (w&3)*16)   covering [32]x[64]
  //  B1 / C      :  mB = (w&1)*16, n-strips (w>>1)*2+{0,1}  covering [32]x[128]
  int mA = (w >> 2) * 16, nA = (w & 3) * 16;
  int mB = (w & 1) * 16;

  // ---- phase A: T1 = X_tile @ u1[e]   (M=32,N=64,K=2048) ----
  f32x4 accA = {0.f, 0.f, 0.f, 0.f};
  for (int kc = 0; kc < D; kc += KC){
    __syncthreads();
    for (int idx = tid; idx < TILE_M * KC; idx += 512){   // 8 iters
      int r = idx >> 7, c = idx & (KC - 1);
      Xs[r * PK + c] = f2b(x[(size_t)s_tok[r] * D + kc + c]);
    }
    for (int idx = tid; idx < 64 * KC; idx += 512){       // 16 iters, transpose u1
      int r = idx & 63, k = idx >> 6;
      U1T[r * PK + k] = f2b(u1[((size_t)e * D + kc + k) * R + r]);
    }
    __syncthreads();
    #pragma unroll
    for (int ks = 0; ks < 4; ++ks)
      accA = __builtin_amdgcn_mfma_f32_16x16x32_bf16(
          ldfrag(Xs, mA, ks * 32, PK, lane),
          ldfrag(U1T, nA, ks * 32, PK, lane), accA, 0, 0, 0);
  }
  { // T1 -> LDS bf16 (C-layout: col=lane&15, row=(lane>>4)*4+j)
    int col = nA + (lane & 15);
    #pragma unroll
    for (int j = 0; j < 4; ++j)
      T1s[(mA + (lane >> 4) * 4 + j) * PR + col] = f2b(accA[j]);
  }

  // ---- phase B: T2 = relu(T1 @ v1 + b1) @ u2, fused per 128-wide h-chunk ----
  f32x4 accT2 = {0.f, 0.f, 0.f, 0.f};
  for (int hc = 0; hc < H; hc += KC){
    __syncthreads();
    for (int idx = tid; idx < 128 * 64; idx += 512){      // transpose v1 -> [h][r]
      int h = idx & 127, r = idx >> 7;
      V1T[h * PR + r] = f2b(v1[((size_t)e * R + r) * H + hc + h]);
    }
    for (int idx = tid; idx < 64 * 128; idx += 512){      // transpose u2 -> [r][h]
      int r = idx & 63, h = idx >> 6;
      U2T[r * PK + h] = f2b(u2[((size_t)e * H + hc + h) * R + r]);
    }
    __syncthreads();
    // B1: Hs = relu(T1s @ V1T + b1)
    #pragma unroll
    for (int t = 0; t < 2; ++t){
      int n0 = ((w >> 1) * 2 + t) * 16;
      f32x4 acc = {0.f, 0.f, 0.f, 0.f};
      #pragma unroll
      for (int ks = 0; ks < 2; ++ks)
        acc = __builtin_amdgcn_mfma_f32_16x16x32_bf16(
            ldfrag(T1s, mB, ks * 32, PR, lane),
            ldfrag(V1T, n0, ks * 32, PR, lane), acc, 0, 0, 0);
      int hcol = n0 + (lane & 15);
      float b1v = b1[(size_t)e * H + hc + hcol];
      #pragma unroll
      for (int j = 0; j < 4; ++j){
        float v = acc[j] + b1v;
        Hs[(mB + (lane >> 4) * 4 + j) * PK + hcol] = f2b(v > 0.f ? v : 0.f);
      }
    }
    __syncthreads();
    // B2: accT2 += Hs @ U2T
    #pragma unroll
    for (int ks = 0; ks < 4; ++ks)
      accT2 = __builtin_amdgcn_mfma_f32_16x16x32_bf16(
          ldfrag(Hs, mA, ks * 32, PK, lane),
          ldfrag(U2T, nA, ks * 32, PK, lane), accT2, 0, 0, 0);
  }
  {
    int col = nA + (lane & 15);
    #pragma unroll
    for (int j = 0; j < 4; ++j)
      T2s[(mA + (lane >> 4) * 4 + j) * PR + col] = f2b(accT2[j]);
  }

  // ---- phase C: out[tok] += wt * (T2 @ v2[e] + b2) ----
  for (int dc = 0; dc < D; dc += KC){
    __syncthreads();
    for (int idx = tid; idx < 128 * 64; idx += 512){      // transpose v2 -> [d][r]
      int d = idx & 127, r = idx >> 7;
      V2T[d * PR + r] = f2b(v2[((size_t)e * R + r) * D + dc + d]);
    }
    __syncthreads();
    #pragma unroll
    for (int t = 0; t < 2; ++t){
      int n0 = ((w >> 1) * 2 + t) * 16;
      f32x4 acc = {0.f, 0.f, 0.f, 0.f};
      #pragma unroll
      for (int ks = 0; ks < 2; ++ks)
        acc = __builtin_amdgcn_mfma_f32_16x16x32_bf16(
            ldfrag(T2s, mB, ks * 32, PR, lane),
            ldfrag(V2T, n0, ks * 32, PR, lane), acc, 0, 0, 0);
      int d = dc + n0 + (lane & 15);
      float b2v = b2[(size_t)e * D + d];
      #pragma unroll
      for (int j = 0; j < 4; ++j){
        int row = mB + (lane >> 4) * 4 + j;
        float yv = acc[j] + b2v;
        atomicAdd(&out[(size_t)s_tok[row] * D + d], s_wt[row] * yv);
      }
    }
  }
}

extern "C" void kernel_launch(void* const* d_in, const int* in_sizes, int n_in,
                              void* d_out, int out_size, void* d_ws, size_t ws_size,
                              hipStream_t stream)
{
  const float* x  = (const float*)d_in[0];
  const float* u1 = (const float*)d_in[1];
  const float* v1 = (const float*)d_in[2];
  const float* b1 = (const float*)d_in[3];
  const float* u2 = (const float*)d_in[4];
  const float* v2 = (const float*)d_in[5];
  const float* b2 = (const float*)d_in[6];
  const float* gw = (const float*)d_in[7];
  const float* gb = (const float*)d_in[8];
  float* out = (float*)d_out;

  int*   cnt = (int*)d_ws;
  int*   lst = cnt + E;                 // [E][NTOK] token ids
  float* wl  = (float*)(lst + E * NTOK);// [E][NTOK] combine weights

  hipMemsetAsync(cnt, 0, E * sizeof(int), stream);
  hipMemsetAsync(out, 0, (size_t)NTOK * D * sizeof(float), stream);

  gate_kernel<<<NTOK / 4, 256, 0, stream>>>(x, gw, gb, cnt, lst, wl);

  dim3 grid(NTOK / TILE_M, E);          // covers worst-case routing skew
  expert_kernel<<<grid, 512, 0, stream>>>(x, u1, v1, b1, u2, v2, b2,
                                          cnt, lst, wl, out);
}

// Round 2
// 484.306 us; speedup vs baseline: 1.2875x; 1.2875x over previous
//
#include <hip/hip_runtime.h>
#include <hip/hip_bf16.h>

#define E 8
#define D 2048
#define H 8192
#define R 64
#define NTOK 4096

typedef __attribute__((ext_vector_type(8))) short bf16x8;
typedef __attribute__((ext_vector_type(4))) float f32x4;

__device__ __forceinline__ unsigned short f2b(float f){
  union { __hip_bfloat16 h; unsigned short u; } cv;
  cv.h = __float2bfloat16(f);
  return cv.u;
}
__device__ __forceinline__ float b2f(unsigned short u){
  union { unsigned int i; float f; } cv; cv.i = ((unsigned int)u) << 16; return cv.f;
}

// MFMA 16x16x32 fragment from [row][k] LDS tile (k 16B-aligned chunks)
__device__ __forceinline__ bf16x8 ldfrag(const unsigned short* base, int row0, int k0,
                                         int pitch, int lane){
  return *reinterpret_cast<const bf16x8*>(base + (row0 + (lane & 15)) * pitch
                                          + k0 + ((lane >> 4) << 3));
}

// ---------------- pack x -> bf16 ----------------
__global__ __launch_bounds__(256) void pack_x_kernel(const float* __restrict__ x,
                                                     unsigned short* __restrict__ xb){
  size_t i = ((size_t)blockIdx.x * 256 + threadIdx.x) * 8;
  float4 a = *reinterpret_cast<const float4*>(x + i);
  float4 b = *reinterpret_cast<const float4*>(x + i + 4);
  unsigned short o[8] = { f2b(a.x), f2b(a.y), f2b(a.z), f2b(a.w),
                          f2b(b.x), f2b(b.y), f2b(b.z), f2b(b.w) };
  *reinterpret_cast<bf16x8*>(xb + i) = *reinterpret_cast<bf16x8*>(o);
}

// ---------------- transpose-pack: src[e][RS][CS] f32 -> dst[e][CS][RS] bf16 ----------------
// 64x64 tiles: coalesced 2B writes (lanes = consecutive dst elems), per-lane 64B-line reads.
__global__ __launch_bounds__(256) void pack_tr(const float* __restrict__ src,
                                               unsigned short* __restrict__ dst,
                                               int RS, int CS){
  int e = blockIdx.z;
  const float* s = src + (size_t)e * RS * CS;
  unsigned short* d = dst + (size_t)e * RS * CS;
  int c0 = blockIdx.x * 64, r0 = blockIdx.y * 64;
  int l = threadIdx.x & 63, cb = (threadIdx.x >> 6) * 16;
  int r = r0 + l;
  const float4* sp = reinterpret_cast<const float4*>(s + (size_t)r * CS + c0 + cb);
  float v[16];
  #pragma unroll
  for (int q = 0; q < 4; ++q){
    float4 t = sp[q];
    v[q*4] = t.x; v[q*4+1] = t.y; v[q*4+2] = t.z; v[q*4+3] = t.w;
  }
  #pragma unroll
  for (int j = 0; j < 16; ++j)
    d[(size_t)(c0 + cb + j) * RS + r] = f2b(v[j]);
}

// ---------------- gate: f32 logits, top-2, renorm, expert lists + token map ----------------
__global__ __launch_bounds__(256) void gate_kernel(
    const float* __restrict__ x, const float* __restrict__ gw,
    const float* __restrict__ gb, int* __restrict__ cnt,
    int* __restrict__ lst, int* __restrict__ tsl)
{
  int wid  = threadIdx.x >> 6;
  int lane = threadIdx.x & 63;
  int n = blockIdx.x * 4 + wid;

  const float* xr = x + (size_t)n * D;
  float acc[E];
  #pragma unroll
  for (int e = 0; e < E; ++e) acc[e] = 0.f;
  for (int i = 0; i < D / 64; ++i){
    int dd = i * 64 + lane;
    float xv = xr[dd];
    #pragma unroll
    for (int e = 0; e < E; ++e) acc[e] += xv * gw[e * D + dd];
  }
  #pragma unroll
  for (int e = 0; e < E; ++e){
    float v = acc[e];
    for (int off = 32; off; off >>= 1) v += __shfl_xor(v, off, 64);
    acc[e] = v + gb[e];
  }
  if (lane == 0){
    float l0 = -1e30f, l1 = -1e30f; int i0 = 0, i1 = 0;
    #pragma unroll
    for (int e = 0; e < E; ++e){
      float v = acc[e];
      if (v > l0){ l1 = l0; i1 = i0; l0 = v; i0 = e; }
      else if (v > l1){ l1 = v; i1 = e; }
    }
    float t  = expf(l1 - l0);
    float w0 = 1.f / (1.f + t);
    float w1 = t * w0;
    int p0 = atomicAdd(&cnt[i0], 1);
    lst[i0 * NTOK + p0] = n;
    int p1 = atomicAdd(&cnt[i1], 1);
    lst[i1 * NTOK + p1] = n;
    int* ts = tsl + n * 8;
    ts[0] = i0; ts[1] = p0; ts[2] = __float_as_int(w0);
    ts[3] = i1; ts[4] = p1; ts[5] = __float_as_int(w1);
  }
}

// ---------------- T1 = X_gather @ u1[e]  (per 64-slot tile) ----------------
__global__ __launch_bounds__(256) void t1_kernel(
    const unsigned short* __restrict__ xb, const unsigned short* __restrict__ u1p,
    const int* __restrict__ cnt, const int* __restrict__ lst,
    unsigned short* __restrict__ T1buf)
{
  int e = blockIdx.y;
  int nc = cnt[e];
  int t0 = blockIdx.x * 64;
  if (t0 >= nc) return;

  __shared__ int s_tok[64];
  __shared__ unsigned short Xs[64 * 136];
  __shared__ unsigned short U1s[64 * 136];
  int tid = threadIdx.x, w = tid >> 6, lane = tid & 63;

  if (tid < 64) s_tok[tid] = lst[e * NTOK + min(t0 + tid, nc - 1)];
  __syncthreads();

  int mA = (w & 1) * 32, nA = (w >> 1) * 32;
  f32x4 z = {0.f, 0.f, 0.f, 0.f};
  f32x4 acc[2][2] = {{z, z}, {z, z}};

  for (int kc = 0; kc < D; kc += 128){
    #pragma unroll
    for (int s = 0; s < 4; ++s){
      int i = tid + s * 256;
      int rr = i >> 4, c = (i & 15) * 8;
      *reinterpret_cast<bf16x8*>(&Xs[rr * 136 + c]) =
        *reinterpret_cast<const bf16x8*>(&xb[(size_t)s_tok[rr] * D + kc + c]);
      *reinterpret_cast<bf16x8*>(&U1s[rr * 136 + c]) =
        *reinterpret_cast<const bf16x8*>(&u1p[((size_t)e * R + rr) * D + kc + c]);
    }
    __syncthreads();
    #pragma unroll
    for (int ks = 0; ks < 4; ++ks)
      #pragma unroll
      for (int i = 0; i < 2; ++i)
        #pragma unroll
        for (int j = 0; j < 2; ++j)
          acc[i][j] = __builtin_amdgcn_mfma_f32_16x16x32_bf16(
              ldfrag(Xs, mA + i * 16, ks * 32, 136, lane),
              ldfrag(U1s, nA + j * 16, ks * 32, 136, lane), acc[i][j], 0, 0, 0);
    __syncthreads();
  }
  #pragma unroll
  for (int i = 0; i < 2; ++i)
    #pragma unroll
    for (int j = 0; j < 2; ++j){
      int col = nA + j * 16 + (lane & 15);
      #pragma unroll
      for (int q = 0; q < 4; ++q){
        int row = mA + i * 16 + ((lane >> 4) << 2) + q;
        T1buf[((size_t)e * NTOK + t0 + row) * R + col] = f2b(acc[i][j][q]);
      }
    }
}

// ---------------- mid: T2[slot][r] += relu(T1 @ v1 + b1) @ u2 over an H-chunk ----------------
// grid (tgroup=16, hchunk=8, e=8); block 512. Each block: up to 4 token-tiles (64 each),
// H-chunk of 1024 in 8 sub-chunks of 128; T2 partial accumulated in regs, atomicAdd at end.
__global__ __launch_bounds__(512) void mid_kernel(
    const unsigned short* __restrict__ T1buf, const unsigned short* __restrict__ v1p,
    const unsigned short* __restrict__ u2p, const float* __restrict__ b1,
    const int* __restrict__ cnt, float* __restrict__ T2acc)
{
  int e = blockIdx.z;
  int hc0 = blockIdx.y * 1024;
  int nc = cnt[e];
  int tiles = (nc + 63) >> 6;
  int tbase = blockIdx.x * 4;
  if (tbase >= tiles) return;
  int nt = min(4, tiles - tbase);

  __shared__ unsigned short T1s[4 * 64 * 72];
  __shared__ unsigned short v1s[128 * 72];
  __shared__ unsigned short u2s[64 * 136];
  __shared__ unsigned short Hs[64 * 136];

  int tid = threadIdx.x, w = tid >> 6, lane = tid & 63;

  for (int i = tid; i < nt * 512; i += 512){           // bf16x8 vec ids, 512 per tile
    int t = i >> 9, vid = i & 511;
    int rr = vid >> 3, c = (vid & 7) * 8;
    *reinterpret_cast<bf16x8*>(&T1s[(t * 64 + rr) * 72 + c]) =
      *reinterpret_cast<const bf16x8*>(&T1buf[((size_t)e * NTOK + (tbase + t) * 64 + rr) * R + c]);
  }

  f32x4 z = {0.f, 0.f, 0.f, 0.f};
  f32x4 acc[4][2] = {{z, z}, {z, z}, {z, z}, {z, z}};
  int m1 = (w & 1) * 32, n1 = (w >> 1) * 32;           // B1 map: 64x128
  int m2 = (w & 3) * 16, r2 = (w >> 2) * 32;           // B2 map: 64x64

  for (int hs = 0; hs < 1024; hs += 128){
    int hb = hc0 + hs;
    #pragma unroll
    for (int s = 0; s < 2; ++s){
      int i = tid + s * 512;
      int hr = i >> 3, c = (i & 7) * 8;                // v1s [128][72]
      *reinterpret_cast<bf16x8*>(&v1s[hr * 72 + c]) =
        *reinterpret_cast<const bf16x8*>(&v1p[((size_t)e * H + hb + hr) * R + c]);
      int rr = i >> 4, c2 = (i & 15) * 8;              // u2s [64][136]
      *reinterpret_cast<bf16x8*>(&u2s[rr * 136 + c2]) =
        *reinterpret_cast<const bf16x8*>(&u2p[((size_t)e * R + rr) * H + hb + c2]);
    }
    __syncthreads();

    #pragma unroll
    for (int t = 0; t < 4; ++t){
      if (t < nt){
        const unsigned short* T1t = T1s + t * 64 * 72;
        #pragma unroll
        for (int i = 0; i < 2; ++i)
          #pragma unroll
          for (int j = 0; j < 2; ++j){
            f32x4 a = z;
            #pragma unroll
            for (int ks = 0; ks < 2; ++ks)
              a = __builtin_amdgcn_mfma_f32_16x16x32_bf16(
                  ldfrag(T1t, m1 + i * 16, ks * 32, 72, lane),
                  ldfrag(v1s, n1 + j * 16, ks * 32, 72, lane), a, 0, 0, 0);
            int hcol = n1 + j * 16 + (lane & 15);
            float bv = b1[(size_t)e * H + hb + hcol];
            #pragma unroll
            for (int q = 0; q < 4; ++q){
              float vv = a[q] + bv;
              Hs[(m1 + i * 16 + ((lane >> 4) << 2) + q) * 136 + hcol] = f2b(vv > 0.f ? vv : 0.f);
            }
          }
        __syncthreads();
        #pragma unroll
        for (int j = 0; j < 2; ++j)
          #pragma unroll
          for (int ks = 0; ks < 4; ++ks)
            acc[t][j] = __builtin_amdgcn_mfma_f32_16x16x32_bf16(
                ldfrag(Hs, m2, ks * 32, 136, lane),
                ldfrag(u2s, r2 + j * 16, ks * 32, 136, lane), acc[t][j], 0, 0, 0);
        __syncthreads();
      }
    }
  }
  #pragma unroll
  for (int t = 0; t < 4; ++t)
    if (t < nt){
      #pragma unroll
      for (int j = 0; j < 2; ++j){
        int col = r2 + j * 16 + (lane & 15);
        #pragma unroll
        for (int q = 0; q < 4; ++q){
          int row = m2 + ((lane >> 4) << 2) + q;
          int slot = (tbase + t) * 64 + row;
          atomicAdd(&T2acc[((size_t)e * NTOK + slot) * R + col], acc[t][j][q]);
        }
      }
    }
}

// ---------------- out: y[slot] = T2 @ v2[e] + b2  -> compact bf16 y-buffer ----------------
__global__ __launch_bounds__(512) void out_kernel(
    const float* __restrict__ T2acc, const unsigned short* __restrict__ v2p,
    const float* __restrict__ b2, const int* __restrict__ cnt,
    unsigned short* __restrict__ yb)
{
  int e = blockIdx.y;
  int nc = cnt[e];
  int t0 = blockIdx.x * 64;
  if (t0 >= nc) return;
  int base = 0;
  #pragma unroll
  for (int i = 0; i < E; ++i) base += (i < e) ? cnt[i] : 0;

  __shared__ unsigned short T2s[64 * 72];
  __shared__ unsigned short v2s[128 * 72];
  int tid = threadIdx.x, w = tid >> 6, lane = tid & 63;

  #pragma unroll
  for (int s = 0; s < 2; ++s){
    int i = tid + s * 512;                              // f32x4 ids, 1024 total
    int rr = i >> 4, c = (i & 15) * 4;
    float4 t = *reinterpret_cast<const float4*>(&T2acc[((size_t)e * NTOK + t0 + rr) * R + c]);
    unsigned short o[4] = { f2b(t.x), f2b(t.y), f2b(t.z), f2b(t.w) };
    *reinterpret_cast<ushort4*>(&T2s[rr * 72 + c]) = *reinterpret_cast<ushort4*>(o);
  }
  __syncthreads();

  int m1 = (w & 1) * 32, n1 = (w >> 1) * 32;
  f32x4 z = {0.f, 0.f, 0.f, 0.f};
  for (int dc = 0; dc < D; dc += 128){
    #pragma unroll
    for (int s = 0; s < 2; ++s){
      int i = tid + s * 512;
      int rr = i >> 3, c = (i & 7) * 8;                 // v2s [128][72]
      *reinterpret_cast<bf16x8*>(&v2s[rr * 72 + c]) =
        *reinterpret_cast<const bf16x8*>(&v2p[((size_t)e * D + dc + rr) * R + c]);
    }
    __syncthreads();
    #pragma unroll
    for (int i = 0; i < 2; ++i)
      #pragma unroll
      for (int j = 0; j < 2; ++j){
        f32x4 a = z;
        #pragma unroll
        for (int ks = 0; ks < 2; ++ks)
          a = __builtin_amdgcn_mfma_f32_16x16x32_bf16(
              ldfrag(T2s, m1 + i * 16, ks * 32, 72, lane),
              ldfrag(v2s, n1 + j * 16, ks * 32, 72, lane), a, 0, 0, 0);
        int dcol = dc + n1 + j * 16 + (lane & 15);
        float bv = b2[(size_t)e * D + dcol];
        #pragma unroll
        for (int q = 0; q < 4; ++q){
          int row = m1 + i * 16 + ((lane >> 4) << 2) + q;
          if (t0 + row < nc)
            yb[((size_t)(base + t0 + row)) * D + dcol] = f2b(a[q] + bv);
        }
      }
    __syncthreads();
  }
}

// ---------------- combine: out[tok] = w0*y[g0] + w1*y[g1] ----------------
__global__ __launch_bounds__(256) void combine_kernel(
    const unsigned short* __restrict__ yb, const int* __restrict__ tsl,
    const int* __restrict__ cnt, float* __restrict__ out)
{
  int tok = blockIdx.x;
  int d0 = threadIdx.x * 8;
  const int* ts = tsl + tok * 8;
  int e0 = ts[0], p0 = ts[1]; float w0 = __int_as_float(ts[2]);
  int e1 = ts[3], p1 = ts[4]; float w1 = __int_as_float(ts[5]);
  int b0 = 0, b1s = 0;
  #pragma unroll
  for (int i = 0; i < E; ++i){
    int c = cnt[i];
    b0  += (i < e0) ? c : 0;
    b1s += (i < e1) ? c : 0;
  }
  bf16x8 y0 = *reinterpret_cast<const bf16x8*>(&yb[((size_t)(b0 + p0)) * D + d0]);
  bf16x8 y1 = *reinterpret_cast<const bf16x8*>(&yb[((size_t)(b1s + p1)) * D + d0]);
  float o[8];
  #pragma unroll
  for (int j = 0; j < 8; ++j)
    o[j] = w0 * b2f((unsigned short)y0[j]) + w1 * b2f((unsigned short)y1[j]);
  *reinterpret_cast<float4*>(&out[(size_t)tok * D + d0])     = *reinterpret_cast<float4*>(&o[0]);
  *reinterpret_cast<float4*>(&out[(size_t)tok * D + d0 + 4]) = *reinterpret_cast<float4*>(&o[4]);
}

extern "C" void kernel_launch(void* const* d_in, const int* in_sizes, int n_in,
                              void* d_out, int out_size, void* d_ws, size_t ws_size,
                              hipStream_t stream)
{
  const float* x  = (const float*)d_in[0];
  const float* u1 = (const float*)d_in[1];
  const float* v1 = (const float*)d_in[2];
  const float* b1 = (const float*)d_in[3];
  const float* u2 = (const float*)d_in[4];
  const float* v2 = (const float*)d_in[5];
  const float* b2 = (const float*)d_in[6];
  const float* gw = (const float*)d_in[7];
  const float* gb = (const float*)d_in[8];
  float* out = (float*)d_out;

  const size_t SZ_XB  = (size_t)NTOK * D * 2;   // 16 MiB
  const size_t SZ_U1P = (size_t)E * R * D * 2;  //  2 MiB
  const size_t SZ_V1P = (size_t)E * H * R * 2;  //  8 MiB
  const size_t SZ_U2P = (size_t)E * R * H * 2;  //  8 MiB
  const size_t SZ_V2P = (size_t)E * D * R * 2;  //  2 MiB
  const size_t SZ_T1  = (size_t)E * NTOK * R * 2;
  const size_t SZ_T2  = (size_t)E * NTOK * R * 4;

  char* ws = (char*)d_ws;
  size_t o = 0;
  auto take = [&](size_t b){ void* p = ws + o; o = (o + b + 255) & ~(size_t)255; return p; };
  int* cnt = (int*)take(E * 4);
  int* lst = (int*)take((size_t)E * NTOK * 4);
  int* tsl = (int*)take((size_t)NTOK * 8 * 4);
  char* A  = (char*)take(SZ_XB + SZ_U1P + SZ_V1P + SZ_U2P);   // 34 MiB
  unsigned short* xb  = (unsigned short*)A;
  unsigned short* u1p = (unsigned short*)(A + SZ_XB);
  unsigned short* v1p = (unsigned short*)(A + SZ_XB + SZ_U1P);
  unsigned short* u2p = (unsigned short*)(A + SZ_XB + SZ_U1P + SZ_V1P);
  unsigned short* yb  = (unsigned short*)A;                   // alias: dead by out_kernel
  unsigned short* v2p = (unsigned short*)take(SZ_V2P);
  unsigned short* T1buf = (unsigned short*)take(SZ_T1);
  float* T2acc = (float*)take(SZ_T2);

  hipMemsetAsync(cnt, 0, E * 4, stream);
  hipMemsetAsync(T2acc, 0, SZ_T2, stream);

  gate_kernel<<<NTOK / 4, 256, 0, stream>>>(x, gw, gb, cnt, lst, tsl);
  pack_x_kernel<<<(NTOK * D / 8) / 256, 256, 0, stream>>>(x, xb);
  pack_tr<<<dim3(1, D / 64, E), 256, 0, stream>>>(u1, u1p, D, R);   // -> [r][d]
  pack_tr<<<dim3(H / 64, 1, E), 256, 0, stream>>>(v1, v1p, R, H);   // -> [h][r]
  pack_tr<<<dim3(1, H / 64, E), 256, 0, stream>>>(u2, u2p, H, R);   // -> [r][h]
  pack_tr<<<dim3(D / 64, 1, E), 256, 0, stream>>>(v2, v2p, R, D);   // -> [d][r]

  t1_kernel<<<dim3(NTOK / 64, E), 256, 0, stream>>>(xb, u1p, cnt, lst, T1buf);
  mid_kernel<<<dim3(16, H / 1024, E), 512, 0, stream>>>(T1buf, v1p, u2p, b1, cnt, T2acc);
  out_kernel<<<dim3(NTOK / 64, E), 512, 0, stream>>>(T2acc, v2p, b2, cnt, yb);
  combine_kernel<<<NTOK, 256, 0, stream>>>(yb, tsl, cnt, out);
}

// Round 5
// 368.491 us; speedup vs baseline: 1.6921x; 1.3143x over previous
//
#include <hip/hip_runtime.h>
#include <hip/hip_bf16.h>

#define E 8
#define D 2048
#define H 8192
#define R 64
#define NTOK 4096
#define HSPLIT 4
#define HPER (H / HSPLIT)   // 2048

typedef __attribute__((ext_vector_type(8))) short bf16x8;
typedef __attribute__((ext_vector_type(4))) float f32x4;

__device__ __forceinline__ unsigned short f2b(float f){
  union { __hip_bfloat16 h; unsigned short u; } cv;
  cv.h = __float2bfloat16(f);
  return cv.u;
}
__device__ __forceinline__ float b2f(unsigned short u){
  union { unsigned int i; float f; } cv; cv.i = ((unsigned int)u) << 16; return cv.f;
}

// MFMA 16x16x32 fragment from [row][k] LDS tile (k in 16B-aligned chunks)
__device__ __forceinline__ bf16x8 ldfrag(const unsigned short* base, int row0, int k0,
                                         int pitch, int lane){
  return *reinterpret_cast<const bf16x8*>(base + (row0 + (lane & 15)) * pitch
                                          + k0 + ((lane >> 4) << 3));
}

// ---------------- transpose-pack: src[e][RS][CS] f32 -> dst[e][CS][RS] bf16 ----------------
__global__ __launch_bounds__(256) void pack_tr(const float* __restrict__ src,
                                               unsigned short* __restrict__ dst,
                                               int RS, int CS){
  int e = blockIdx.z;
  const float* s = src + (size_t)e * RS * CS;
  unsigned short* d = dst + (size_t)e * RS * CS;
  int c0 = blockIdx.x * 64, r0 = blockIdx.y * 64;
  int l = threadIdx.x & 63, cb = (threadIdx.x >> 6) * 16;
  int r = r0 + l;
  const float4* sp = reinterpret_cast<const float4*>(s + (size_t)r * CS + c0 + cb);
  float v[16];
  #pragma unroll
  for (int q = 0; q < 4; ++q){
    float4 t = sp[q];
    v[q*4] = t.x; v[q*4+1] = t.y; v[q*4+2] = t.z; v[q*4+3] = t.w;
  }
  #pragma unroll
  for (int j = 0; j < 16; ++j)
    d[(size_t)(c0 + cb + j) * RS + r] = f2b(v[j]);
}

// ---------------- gate (fused x->bf16 pack): f32 logits, top-2, renorm ----------------
__global__ __launch_bounds__(256) void gate_kernel(
    const float* __restrict__ x, const float* __restrict__ gw,
    const float* __restrict__ gb, int* __restrict__ cnt,
    int* __restrict__ lst, int* __restrict__ tsl,
    unsigned short* __restrict__ xb)
{
  int wid  = threadIdx.x >> 6;
  int lane = threadIdx.x & 63;
  int n = blockIdx.x * 4 + wid;

  const float* xr = x + (size_t)n * D;
  unsigned short* xw = xb + (size_t)n * D;
  float acc[E];
  #pragma unroll
  for (int e = 0; e < E; ++e) acc[e] = 0.f;

  for (int i = 0; i < D / 256; ++i){          // 8 iters, float4 per lane
    int dd = i * 256 + lane * 4;
    float4 xv = *reinterpret_cast<const float4*>(xr + dd);
    unsigned short o[4] = { f2b(xv.x), f2b(xv.y), f2b(xv.z), f2b(xv.w) };
    *reinterpret_cast<ushort4*>(xw + dd) = *reinterpret_cast<ushort4*>(o);
    #pragma unroll
    for (int e = 0; e < E; ++e){
      float4 g = *reinterpret_cast<const float4*>(gw + (size_t)e * D + dd);
      acc[e] += xv.x * g.x + xv.y * g.y + xv.z * g.z + xv.w * g.w;
    }
  }
  #pragma unroll
  for (int e = 0; e < E; ++e){
    float v = acc[e];
    for (int off = 32; off; off >>= 1) v += __shfl_xor(v, off, 64);
    acc[e] = v + gb[e];
  }
  if (lane == 0){
    float l0 = -1e30f, l1 = -1e30f; int i0 = 0, i1 = 0;
    #pragma unroll
    for (int e = 0; e < E; ++e){
      float v = acc[e];
      if (v > l0){ l1 = l0; i1 = i0; l0 = v; i0 = e; }
      else if (v > l1){ l1 = v; i1 = e; }
    }
    float t  = expf(l1 - l0);
    float w0 = 1.f / (1.f + t);
    float w1 = t * w0;
    int p0 = atomicAdd(&cnt[i0], 1);
    lst[i0 * NTOK + p0] = n;
    int p1 = atomicAdd(&cnt[i1], 1);
    lst[i1 * NTOK + p1] = n;
    int* ts = tsl + n * 8;
    ts[0] = i0; ts[1] = p0; ts[2] = __float_as_int(w0);
    ts[3] = i1; ts[4] = p1; ts[5] = __float_as_int(w1);
  }
}

// ---------------- T1 = X_gather @ u1[e]  (64-slot tile, 256 thr) ----------------
__global__ __launch_bounds__(256) void t1_kernel(
    const unsigned short* __restrict__ xb, const unsigned short* __restrict__ u1p,
    const int* __restrict__ cnt, const int* __restrict__ lst,
    unsigned short* __restrict__ T1buf)
{
  int e = blockIdx.y;
  int nc = cnt[e];
  int t0 = blockIdx.x * 64;
  if (t0 >= nc) return;

  __shared__ int s_tok[64];
  __shared__ unsigned short Xs[64 * 136];
  __shared__ unsigned short U1s[64 * 136];
  int tid = threadIdx.x, w = tid >> 6, lane = tid & 63;

  if (tid < 64) s_tok[tid] = lst[e * NTOK + min(t0 + tid, nc - 1)];
  __syncthreads();

  int m = (w & 3) * 16;
  f32x4 z = {0.f, 0.f, 0.f, 0.f};
  f32x4 acc[4] = {z, z, z, z};

  for (int kc = 0; kc < D; kc += 128){
    __syncthreads();
    #pragma unroll
    for (int s = 0; s < 4; ++s){
      int id = tid + s * 256;
      int rr = id >> 4, c = (id & 15) * 8;
      *reinterpret_cast<bf16x8*>(&Xs[rr * 136 + c]) =
        *reinterpret_cast<const bf16x8*>(&xb[(size_t)s_tok[rr] * D + kc + c]);
      *reinterpret_cast<bf16x8*>(&U1s[rr * 136 + c]) =
        *reinterpret_cast<const bf16x8*>(&u1p[((size_t)e * R + rr) * D + kc + c]);
    }
    __syncthreads();
    #pragma unroll
    for (int j = 0; j < 4; ++j)
      #pragma unroll
      for (int ks = 0; ks < 4; ++ks)
        acc[j] = __builtin_amdgcn_mfma_f32_16x16x32_bf16(
            ldfrag(Xs, m, ks * 32, 136, lane),
            ldfrag(U1s, j * 16, ks * 32, 136, lane), acc[j], 0, 0, 0);
  }
  #pragma unroll
  for (int j = 0; j < 4; ++j){
    int col = j * 16 + (lane & 15);
    #pragma unroll
    for (int q = 0; q < 4; ++q){
      int row = m + ((lane >> 4) << 2) + q;
      T1buf[((size_t)e * NTOK + t0 + row) * R + col] = f2b(acc[j][q]);
    }
  }
}

// ---------------- mid: T2 += relu(T1 @ v1 + b1) @ u2  (64 slots x H/4 per block) ----------------
__global__ __launch_bounds__(512, 4) void mid_kernel(
    const unsigned short* __restrict__ T1buf, const unsigned short* __restrict__ v1p,
    const unsigned short* __restrict__ u2p, const float* __restrict__ b1,
    const int* __restrict__ cnt, float* __restrict__ T2acc)
{
  int e = blockIdx.z;
  int nc = cnt[e];
  int t0 = blockIdx.x * 64;
  if (t0 >= nc) return;
  int hc0 = blockIdx.y * HPER;

  __shared__ unsigned short T1s[64 * 72];
  __shared__ unsigned short v1s[128 * 72];
  __shared__ unsigned short u2s[64 * 136];
  __shared__ unsigned short Hs[64 * 136];
  __shared__ float b1s[HPER];

  int tid = threadIdx.x, w = tid >> 6, lane = tid & 63;

  { int rr = tid >> 3, c = (tid & 7) * 8;
    *reinterpret_cast<bf16x8*>(&T1s[rr * 72 + c]) =
      *reinterpret_cast<const bf16x8*>(&T1buf[((size_t)e * NTOK + t0 + rr) * R + c]); }
  for (int i = tid; i < HPER; i += 512) b1s[i] = b1[(size_t)e * H + hc0 + i];

  int m1 = (w & 1) * 32, n1 = (w >> 1) * 32;   // B1: 64x128
  int m2 = (w & 3) * 16, r2 = (w >> 2) * 32;   // B2: 64x64
  f32x4 z = {0.f, 0.f, 0.f, 0.f};
  f32x4 acc[2] = {z, z};

  // register prefetch of subchunk 0 (T14 pattern)
  bf16x8 pv[2], pu[2];
  #pragma unroll
  for (int s = 0; s < 2; ++s){
    int id = tid + s * 512;
    pv[s] = *reinterpret_cast<const bf16x8*>(&v1p[((size_t)e * H + hc0 + (id >> 3)) * R + (id & 7) * 8]);
    pu[s] = *reinterpret_cast<const bf16x8*>(&u2p[((size_t)e * R + (id >> 4)) * H + hc0 + (id & 15) * 8]);
  }

  for (int hs = 0; hs < HPER; hs += 128){
    __syncthreads();                            // prev B2 done reading v1s/u2s
    #pragma unroll
    for (int s = 0; s < 2; ++s){
      int id = tid + s * 512;
      *reinterpret_cast<bf16x8*>(&v1s[(id >> 3) * 72 + (id & 7) * 8]) = pv[s];
      *reinterpret_cast<bf16x8*>(&u2s[(id >> 4) * 136 + (id & 15) * 8]) = pu[s];
    }
    __syncthreads();
    // B1: Hs = relu(T1s @ v1s^T + b1)
    #pragma unroll
    for (int i = 0; i < 2; ++i)
      #pragma unroll
      for (int j = 0; j < 2; ++j){
        f32x4 a = z;
        #pragma unroll
        for (int ks = 0; ks < 2; ++ks)
          a = __builtin_amdgcn_mfma_f32_16x16x32_bf16(
              ldfrag(T1s, m1 + i * 16, ks * 32, 72, lane),
              ldfrag(v1s, n1 + j * 16, ks * 32, 72, lane), a, 0, 0, 0);
        int hcol = n1 + j * 16 + (lane & 15);
        float bv = b1s[hs + hcol];
        #pragma unroll
        for (int q = 0; q < 4; ++q){
          float vv = a[q] + bv;
          Hs[(m1 + i * 16 + ((lane >> 4) << 2) + q) * 136 + hcol] = f2b(vv > 0.f ? vv : 0.f);
        }
      }
    // prefetch next subchunk into regs (overlaps barrier + B2)
    int hn = (hs + 128 < HPER) ? hs + 128 : 0;
    #pragma unroll
    for (int s = 0; s < 2; ++s){
      int id = tid + s * 512;
      pv[s] = *reinterpret_cast<const bf16x8*>(&v1p[((size_t)e * H + hc0 + hn + (id >> 3)) * R + (id & 7) * 8]);
      pu[s] = *reinterpret_cast<const bf16x8*>(&u2p[((size_t)e * R + (id >> 4)) * H + hc0 + hn + (id & 15) * 8]);
    }
    __syncthreads();                            // Hs ready
    // B2: acc += Hs @ u2s^T
    #pragma unroll
    for (int j = 0; j < 2; ++j)
      #pragma unroll
      for (int ks = 0; ks < 4; ++ks)
        acc[j] = __builtin_amdgcn_mfma_f32_16x16x32_bf16(
            ldfrag(Hs, m2, ks * 32, 136, lane),
            ldfrag(u2s, r2 + j * 16, ks * 32, 136, lane), acc[j], 0, 0, 0);
  }
  #pragma unroll
  for (int j = 0; j < 2; ++j){
    int col = r2 + j * 16 + (lane & 15);
    #pragma unroll
    for (int q = 0; q < 4; ++q){
      int row = m2 + ((lane >> 4) << 2) + q;
      atomicAdd(&T2acc[((size_t)e * NTOK + t0 + row) * R + col], acc[j][q]);
    }
  }
}

// ---------------- out: y[slot] = T2 @ v2[e] + b2  -> compact bf16 yb ----------------
__global__ __launch_bounds__(512, 4) void out_kernel(
    const float* __restrict__ T2acc, const unsigned short* __restrict__ v2p,
    const float* __restrict__ b2, const int* __restrict__ cnt,
    unsigned short* __restrict__ yb)
{
  int e = blockIdx.y;
  int nc = cnt[e];
  int t0 = blockIdx.x * 64;
  if (t0 >= nc) return;
  int base = 0;
  #pragma unroll
  for (int i = 0; i < E; ++i) base += (i < e) ? cnt[i] : 0;

  __shared__ unsigned short T2s[64 * 72];
  __shared__ unsigned short v2s[256 * 72];
  __shared__ float b2s[D];
  int tid = threadIdx.x, w = tid >> 6, lane = tid & 63;

  { int rr = tid >> 3, c = (tid & 7) * 8;
    const float* src = &T2acc[((size_t)e * NTOK + t0 + rr) * R + c];
    float4 a = *reinterpret_cast<const float4*>(src);
    float4 b = *reinterpret_cast<const float4*>(src + 4);
    unsigned short o[8] = { f2b(a.x), f2b(a.y), f2b(a.z), f2b(a.w),
                            f2b(b.x), f2b(b.y), f2b(b.z), f2b(b.w) };
    *reinterpret_cast<bf16x8*>(&T2s[rr * 72 + c]) = *reinterpret_cast<bf16x8*>(o); }
  for (int i = tid; i < D; i += 512) b2s[i] = b2[(size_t)e * D + i];

  int m1 = (w & 1) * 32, nb = (w >> 1) * 64;
  f32x4 z = {0.f, 0.f, 0.f, 0.f};

  for (int dc = 0; dc < D; dc += 256){
    __syncthreads();
    #pragma unroll
    for (int s = 0; s < 4; ++s){
      int id = tid + s * 512;
      int rr = id >> 3, c = (id & 7) * 8;
      *reinterpret_cast<bf16x8*>(&v2s[rr * 72 + c]) =
        *reinterpret_cast<const bf16x8*>(&v2p[((size_t)e * D + dc + rr) * R + c]);
    }
    __syncthreads();
    #pragma unroll
    for (int i = 0; i < 2; ++i)
      #pragma unroll
      for (int j = 0; j < 4; ++j){
        f32x4 a = z;
        #pragma unroll
        for (int ks = 0; ks < 2; ++ks)
          a = __builtin_amdgcn_mfma_f32_16x16x32_bf16(
              ldfrag(T2s, m1 + i * 16, ks * 32, 72, lane),
              ldfrag(v2s, nb + j * 16, ks * 32, 72, lane), a, 0, 0, 0);
        int dcol = dc + nb + j * 16 + (lane & 15);
        float bv = b2s[dcol];
        #pragma unroll
        for (int q = 0; q < 4; ++q){
          int row = m1 + i * 16 + ((lane >> 4) << 2) + q;
          if (t0 + row < nc)
            yb[((size_t)(base + t0 + row)) * D + dcol] = f2b(a[q] + bv);
        }
      }
  }
}

// ---------------- combine: out[tok] = w0*y[g0] + w1*y[g1] ----------------
__global__ __launch_bounds__(256) void combine_kernel(
    const unsigned short* __restrict__ yb, const int* __restrict__ tsl,
    const int* __restrict__ cnt, float* __restrict__ out)
{
  int tok = blockIdx.x;
  int d0 = threadIdx.x * 8;
  const int* ts = tsl + tok * 8;
  int e0 = ts[0], p0 = ts[1]; float w0 = __int_as_float(ts[2]);
  int e1 = ts[3], p1 = ts[4]; float w1 = __int_as_float(ts[5]);
  int b0 = 0, b1s = 0;
  #pragma unroll
  for (int i = 0; i < E; ++i){
    int c = cnt[i];
    b0  += (i < e0) ? c : 0;
    b1s += (i < e1) ? c : 0;
  }
  bf16x8 y0 = *reinterpret_cast<const bf16x8*>(&yb[((size_t)(b0 + p0)) * D + d0]);
  bf16x8 y1 = *reinterpret_cast<const bf16x8*>(&yb[((size_t)(b1s + p1)) * D + d0]);
  float o[8];
  #pragma unroll
  for (int j = 0; j < 8; ++j)
    o[j] = w0 * b2f((unsigned short)y0[j]) + w1 * b2f((unsigned short)y1[j]);
  *reinterpret_cast<float4*>(&out[(size_t)tok * D + d0])     = *reinterpret_cast<float4*>(&o[0]);
  *reinterpret_cast<float4*>(&out[(size_t)tok * D + d0 + 4]) = *reinterpret_cast<float4*>(&o[4]);
}

extern "C" void kernel_launch(void* const* d_in, const int* in_sizes, int n_in,
                              void* d_out, int out_size, void* d_ws, size_t ws_size,
                              hipStream_t stream)
{
  const float* x  = (const float*)d_in[0];
  const float* u1 = (const float*)d_in[1];
  const float* v1 = (const float*)d_in[2];
  const float* b1 = (const float*)d_in[3];
  const float* u2 = (const float*)d_in[4];
  const float* v2 = (const float*)d_in[5];
  const float* b2 = (const float*)d_in[6];
  const float* gw = (const float*)d_in[7];
  const float* gb = (const float*)d_in[8];
  float* out = (float*)d_out;

  const size_t SZ_XB  = (size_t)NTOK * D * 2;   // 16 MiB
  const size_t SZ_U1P = (size_t)E * R * D * 2;  //  2 MiB
  const size_t SZ_V1P = (size_t)E * H * R * 2;  //  8 MiB
  const size_t SZ_U2P = (size_t)E * R * H * 2;  //  8 MiB
  const size_t SZ_V2P = (size_t)E * D * R * 2;  //  2 MiB
  const size_t SZ_T1  = (size_t)E * NTOK * R * 2;
  const size_t SZ_T2  = (size_t)E * NTOK * R * 4;

  char* ws = (char*)d_ws;
  size_t o = 0;
  auto take = [&](size_t b){ void* p = ws + o; o = (o + b + 255) & ~(size_t)255; return p; };
  int* cnt = (int*)take(E * 4);
  int* lst = (int*)take((size_t)E * NTOK * 4);
  int* tsl = (int*)take((size_t)NTOK * 8 * 4);
  char* A  = (char*)take(SZ_XB + SZ_U1P + SZ_V1P + SZ_U2P);   // 34 MiB
  unsigned short* xb  = (unsigned short*)A;
  unsigned short* u1p = (unsigned short*)(A + SZ_XB);
  unsigned short* v1p = (unsigned short*)(A + SZ_XB + SZ_U1P);
  unsigned short* u2p = (unsigned short*)(A + SZ_XB + SZ_U1P + SZ_V1P);
  unsigned short* yb  = (unsigned short*)A;                   // alias: all dead by out_kernel
  unsigned short* v2p = (unsigned short*)take(SZ_V2P);
  unsigned short* T1buf = (unsigned short*)take(SZ_T1);
  float* T2acc = (float*)take(SZ_T2);

  hipMemsetAsync(cnt, 0, E * 4, stream);
  hipMemsetAsync(T2acc, 0, SZ_T2, stream);

  gate_kernel<<<NTOK / 4, 256, 0, stream>>>(x, gw, gb, cnt, lst, tsl, xb);
  pack_tr<<<dim3(1, D / 64, E), 256, 0, stream>>>(u1, u1p, D, R);   // -> [r][d]
  pack_tr<<<dim3(H / 64, 1, E), 256, 0, stream>>>(v1, v1p, R, H);   // -> [h][r]
  pack_tr<<<dim3(1, H / 64, E), 256, 0, stream>>>(u2, u2p, H, R);   // -> [r][h]
  pack_tr<<<dim3(D / 64, 1, E), 256, 0, stream>>>(v2, v2p, R, D);   // -> [d][r]

  t1_kernel<<<dim3(NTOK / 64, E), 256, 0, stream>>>(xb, u1p, cnt, lst, T1buf);
  mid_kernel<<<dim3(NTOK / 64, HSPLIT, E), 512, 0, stream>>>(T1buf, v1p, u2p, b1, cnt, T2acc);
  out_kernel<<<dim3(NTOK / 64, E), 512, 0, stream>>>(T2acc, v2p, b2, cnt, yb);
  combine_kernel<<<NTOK, 256, 0, stream>>>(yb, tsl, cnt, out);
}

// Round 6
// 366.975 us; speedup vs baseline: 1.6991x; 1.0041x over previous
//
#include <hip/hip_runtime.h>
#include <hip/hip_bf16.h>

#define E 8
#define D 2048
#define H 8192
#define R 64
#define NTOK 4096
#define HSPLIT 4
#define HPER (H / HSPLIT)   // 2048

typedef __attribute__((ext_vector_type(8))) short bf16x8;
typedef __attribute__((ext_vector_type(4))) float f32x4;

__device__ __forceinline__ unsigned short f2b(float f){
  union { __hip_bfloat16 h; unsigned short u; } cv;
  cv.h = __float2bfloat16(f);
  return cv.u;
}
__device__ __forceinline__ float b2f(unsigned short u){
  union { unsigned int i; float f; } cv; cv.i = ((unsigned int)u) << 16; return cv.f;
}

// MFMA 16x16x32 fragment from [row][k] LDS tile (k in 16B-aligned chunks)
__device__ __forceinline__ bf16x8 ldfrag(const unsigned short* base, int row0, int k0,
                                         int pitch, int lane){
  return *reinterpret_cast<const bf16x8*>(base + (row0 + (lane & 15)) * pitch
                                          + k0 + ((lane >> 4) << 3));
}

// ---------------- transpose-pack: src[e][RS][CS] f32 -> dst[e][CS][RS] bf16 ----------------
__global__ __launch_bounds__(256) void pack_tr(const float* __restrict__ src,
                                               unsigned short* __restrict__ dst,
                                               int RS, int CS){
  int e = blockIdx.z;
  const float* s = src + (size_t)e * RS * CS;
  unsigned short* d = dst + (size_t)e * RS * CS;
  int c0 = blockIdx.x * 64, r0 = blockIdx.y * 64;
  int l = threadIdx.x & 63, cb = (threadIdx.x >> 6) * 16;
  int r = r0 + l;
  const float4* sp = reinterpret_cast<const float4*>(s + (size_t)r * CS + c0 + cb);
  float v[16];
  #pragma unroll
  for (int q = 0; q < 4; ++q){
    float4 t = sp[q];
    v[q*4] = t.x; v[q*4+1] = t.y; v[q*4+2] = t.z; v[q*4+3] = t.w;
  }
  #pragma unroll
  for (int j = 0; j < 16; ++j)
    d[(size_t)(c0 + cb + j) * RS + r] = f2b(v[j]);
}

// ---------------- gate v3: 4 tokens/wave, gw loads amortized 4x, fused xb pack ----------------
__global__ __launch_bounds__(256) void gate_kernel(
    const float* __restrict__ x, const float* __restrict__ gw,
    const float* __restrict__ gb, int* __restrict__ cnt,
    int* __restrict__ lst, int* __restrict__ tsl,
    unsigned short* __restrict__ xb)
{
  int wid  = threadIdx.x >> 6;
  int lane = threadIdx.x & 63;
  int n0 = blockIdx.x * 16 + wid * 4;     // 4 tokens per wave

  float acc[4][E];
  #pragma unroll
  for (int t = 0; t < 4; ++t)
    #pragma unroll
    for (int e = 0; e < E; ++e) acc[t][e] = 0.f;

  for (int i = 0; i < D / 256; ++i){      // 8 iters
    int dd = i * 256 + lane * 4;
    float4 xv[4];
    #pragma unroll
    for (int t = 0; t < 4; ++t){
      xv[t] = *reinterpret_cast<const float4*>(x + (size_t)(n0 + t) * D + dd);
      unsigned short o[4] = { f2b(xv[t].x), f2b(xv[t].y), f2b(xv[t].z), f2b(xv[t].w) };
      *reinterpret_cast<ushort4*>(xb + (size_t)(n0 + t) * D + dd) = *reinterpret_cast<ushort4*>(o);
    }
    #pragma unroll
    for (int e = 0; e < E; ++e){
      float4 g = *reinterpret_cast<const float4*>(gw + (size_t)e * D + dd);
      #pragma unroll
      for (int t = 0; t < 4; ++t)
        acc[t][e] += xv[t].x * g.x + xv[t].y * g.y + xv[t].z * g.z + xv[t].w * g.w;
    }
  }

  #pragma unroll
  for (int t = 0; t < 4; ++t){
    #pragma unroll
    for (int e = 0; e < E; ++e){
      float v = acc[t][e];
      for (int off = 32; off; off >>= 1) v += __shfl_xor(v, off, 64);
      acc[t][e] = v + gb[e];
    }
    if (lane == 0){
      int n = n0 + t;
      float l0 = -1e30f, l1 = -1e30f; int i0 = 0, i1 = 0;
      #pragma unroll
      for (int e = 0; e < E; ++e){
        float v = acc[t][e];
        if (v > l0){ l1 = l0; i1 = i0; l0 = v; i0 = e; }
        else if (v > l1){ l1 = v; i1 = e; }
      }
      float tt = expf(l1 - l0);
      float w0 = 1.f / (1.f + tt);
      float w1 = tt * w0;
      int p0 = atomicAdd(&cnt[i0], 1);
      lst[i0 * NTOK + p0] = n;
      int p1 = atomicAdd(&cnt[i1], 1);
      lst[i1 * NTOK + p1] = n;
      int* ts = tsl + n * 8;
      ts[0] = i0; ts[1] = p0; ts[2] = __float_as_int(w0);
      ts[3] = i1; ts[4] = p1; ts[5] = __float_as_int(w1);
    }
  }
}

// ---------------- T1 = X_gather @ u1[e]  (64-slot tile, 256 thr) ----------------
__global__ __launch_bounds__(256) void t1_kernel(
    const unsigned short* __restrict__ xb, const unsigned short* __restrict__ u1p,
    const int* __restrict__ cnt, const int* __restrict__ lst,
    unsigned short* __restrict__ T1buf)
{
  int e = blockIdx.y;
  int nc = cnt[e];
  int t0 = blockIdx.x * 64;
  if (t0 >= nc) return;

  __shared__ int s_tok[64];
  __shared__ unsigned short Xs[64 * 136];
  __shared__ unsigned short U1s[64 * 136];
  int tid = threadIdx.x, w = tid >> 6, lane = tid & 63;

  if (tid < 64) s_tok[tid] = lst[e * NTOK + min(t0 + tid, nc - 1)];
  __syncthreads();

  int m = (w & 3) * 16;
  f32x4 z = {0.f, 0.f, 0.f, 0.f};
  f32x4 acc[4] = {z, z, z, z};

  for (int kc = 0; kc < D; kc += 128){
    __syncthreads();
    #pragma unroll
    for (int s = 0; s < 4; ++s){
      int id = tid + s * 256;
      int rr = id >> 4, c = (id & 15) * 8;
      *reinterpret_cast<bf16x8*>(&Xs[rr * 136 + c]) =
        *reinterpret_cast<const bf16x8*>(&xb[(size_t)s_tok[rr] * D + kc + c]);
      *reinterpret_cast<bf16x8*>(&U1s[rr * 136 + c]) =
        *reinterpret_cast<const bf16x8*>(&u1p[((size_t)e * R + rr) * D + kc + c]);
    }
    __syncthreads();
    #pragma unroll
    for (int j = 0; j < 4; ++j)
      #pragma unroll
      for (int ks = 0; ks < 4; ++ks)
        acc[j] = __builtin_amdgcn_mfma_f32_16x16x32_bf16(
            ldfrag(Xs, m, ks * 32, 136, lane),
            ldfrag(U1s, j * 16, ks * 32, 136, lane), acc[j], 0, 0, 0);
  }
  #pragma unroll
  for (int j = 0; j < 4; ++j){
    int col = j * 16 + (lane & 15);
    #pragma unroll
    for (int q = 0; q < 4; ++q){
      int row = m + ((lane >> 4) << 2) + q;
      T1buf[((size_t)e * NTOK + t0 + row) * R + col] = f2b(acc[j][q]);
    }
  }
}

// ---------------- mid: T2 += relu(T1 @ v1 + b1) @ u2  (64 slots x H/4 per block) ----------------
__global__ __launch_bounds__(512, 4) void mid_kernel(
    const unsigned short* __restrict__ T1buf, const unsigned short* __restrict__ v1p,
    const unsigned short* __restrict__ u2p, const float* __restrict__ b1,
    const int* __restrict__ cnt, float* __restrict__ T2acc)
{
  int e = blockIdx.z;
  int nc = cnt[e];
  int t0 = blockIdx.x * 64;
  if (t0 >= nc) return;
  int hc0 = blockIdx.y * HPER;

  __shared__ unsigned short T1s[64 * 72];
  __shared__ unsigned short v1s[128 * 72];
  __shared__ unsigned short u2s[64 * 136];
  __shared__ unsigned short Hs[64 * 136];
  __shared__ float b1s[HPER];

  int tid = threadIdx.x, w = tid >> 6, lane = tid & 63;

  { int rr = tid >> 3, c = (tid & 7) * 8;
    *reinterpret_cast<bf16x8*>(&T1s[rr * 72 + c]) =
      *reinterpret_cast<const bf16x8*>(&T1buf[((size_t)e * NTOK + t0 + rr) * R + c]); }
  for (int i = tid; i < HPER; i += 512) b1s[i] = b1[(size_t)e * H + hc0 + i];

  int m1 = (w & 1) * 32, n1 = (w >> 1) * 32;   // B1: 64x128
  int m2 = (w & 3) * 16, r2 = (w >> 2) * 32;   // B2: 64x64
  f32x4 z = {0.f, 0.f, 0.f, 0.f};
  f32x4 acc[2] = {z, z};

  // register prefetch of subchunk 0 (T14 pattern)
  bf16x8 pv[2], pu[2];
  #pragma unroll
  for (int s = 0; s < 2; ++s){
    int id = tid + s * 512;
    pv[s] = *reinterpret_cast<const bf16x8*>(&v1p[((size_t)e * H + hc0 + (id >> 3)) * R + (id & 7) * 8]);
    pu[s] = *reinterpret_cast<const bf16x8*>(&u2p[((size_t)e * R + (id >> 4)) * H + hc0 + (id & 15) * 8]);
  }

  for (int hs = 0; hs < HPER; hs += 128){
    __syncthreads();                            // prev B2 done reading v1s/u2s
    #pragma unroll
    for (int s = 0; s < 2; ++s){
      int id = tid + s * 512;
      *reinterpret_cast<bf16x8*>(&v1s[(id >> 3) * 72 + (id & 7) * 8]) = pv[s];
      *reinterpret_cast<bf16x8*>(&u2s[(id >> 4) * 136 + (id & 15) * 8]) = pu[s];
    }
    __syncthreads();
    // B1: Hs = relu(T1s @ v1s^T + b1)
    #pragma unroll
    for (int i = 0; i < 2; ++i)
      #pragma unroll
      for (int j = 0; j < 2; ++j){
        f32x4 a = z;
        #pragma unroll
        for (int ks = 0; ks < 2; ++ks)
          a = __builtin_amdgcn_mfma_f32_16x16x32_bf16(
              ldfrag(T1s, m1 + i * 16, ks * 32, 72, lane),
              ldfrag(v1s, n1 + j * 16, ks * 32, 72, lane), a, 0, 0, 0);
        int hcol = n1 + j * 16 + (lane & 15);
        float bv = b1s[hs + hcol];
        #pragma unroll
        for (int q = 0; q < 4; ++q){
          float vv = a[q] + bv;
          Hs[(m1 + i * 16 + ((lane >> 4) << 2) + q) * 136 + hcol] = f2b(vv > 0.f ? vv : 0.f);
        }
      }
    // prefetch next subchunk into regs (overlaps barrier + B2)
    int hn = (hs + 128 < HPER) ? hs + 128 : 0;
    #pragma unroll
    for (int s = 0; s < 2; ++s){
      int id = tid + s * 512;
      pv[s] = *reinterpret_cast<const bf16x8*>(&v1p[((size_t)e * H + hc0 + hn + (id >> 3)) * R + (id & 7) * 8]);
      pu[s] = *reinterpret_cast<const bf16x8*>(&u2p[((size_t)e * R + (id >> 4)) * H + hc0 + hn + (id & 15) * 8]);
    }
    __syncthreads();                            // Hs ready
    // B2: acc += Hs @ u2s^T
    #pragma unroll
    for (int j = 0; j < 2; ++j)
      #pragma unroll
      for (int ks = 0; ks < 4; ++ks)
        acc[j] = __builtin_amdgcn_mfma_f32_16x16x32_bf16(
            ldfrag(Hs, m2, ks * 32, 136, lane),
            ldfrag(u2s, r2 + j * 16, ks * 32, 136, lane), acc[j], 0, 0, 0);
  }
  #pragma unroll
  for (int j = 0; j < 2; ++j){
    int col = r2 + j * 16 + (lane & 15);
    #pragma unroll
    for (int q = 0; q < 4; ++q){
      int row = m2 + ((lane >> 4) << 2) + q;
      atomicAdd(&T2acc[((size_t)e * NTOK + t0 + row) * R + col], acc[j][q]);
    }
  }
}

// ---------------- out: y[slot] = T2 @ v2[e] + b2  -> compact bf16 yb ----------------
__global__ __launch_bounds__(512, 4) void out_kernel(
    const float* __restrict__ T2acc, const unsigned short* __restrict__ v2p,
    const float* __restrict__ b2, const int* __restrict__ cnt,
    unsigned short* __restrict__ yb)
{
  int e = blockIdx.y;
  int nc = cnt[e];
  int t0 = blockIdx.x * 64;
  if (t0 >= nc) return;
  int base = 0;
  #pragma unroll
  for (int i = 0; i < E; ++i) base += (i < e) ? cnt[i] : 0;

  __shared__ unsigned short T2s[64 * 72];
  __shared__ unsigned short v2s[256 * 72];
  __shared__ float b2s[D];
  int tid = threadIdx.x, w = tid >> 6, lane = tid & 63;

  { int rr = tid >> 3, c = (tid & 7) * 8;
    const float* src = &T2acc[((size_t)e * NTOK + t0 + rr) * R + c];
    float4 a = *reinterpret_cast<const float4*>(src);
    float4 b = *reinterpret_cast<const float4*>(src + 4);
    unsigned short o[8] = { f2b(a.x), f2b(a.y), f2b(a.z), f2b(a.w),
                            f2b(b.x), f2b(b.y), f2b(b.z), f2b(b.w) };
    *reinterpret_cast<bf16x8*>(&T2s[rr * 72 + c]) = *reinterpret_cast<bf16x8*>(o); }
  for (int i = tid; i < D; i += 512) b2s[i] = b2[(size_t)e * D + i];

  int m1 = (w & 1) * 32, nb = (w >> 1) * 64;
  f32x4 z = {0.f, 0.f, 0.f, 0.f};

  for (int dc = 0; dc < D; dc += 256){
    __syncthreads();
    #pragma unroll
    for (int s = 0; s < 4; ++s){
      int id = tid + s * 512;
      int rr = id >> 3, c = (id & 7) * 8;
      *reinterpret_cast<bf16x8*>(&v2s[rr * 72 + c]) =
        *reinterpret_cast<const bf16x8*>(&v2p[((size_t)e * D + dc + rr) * R + c]);
    }
    __syncthreads();
    #pragma unroll
    for (int i = 0; i < 2; ++i)
      #pragma unroll
      for (int j = 0; j < 4; ++j){
        f32x4 a = z;
        #pragma unroll
        for (int ks = 0; ks < 2; ++ks)
          a = __builtin_amdgcn_mfma_f32_16x16x32_bf16(
              ldfrag(T2s, m1 + i * 16, ks * 32, 72, lane),
              ldfrag(v2s, nb + j * 16, ks * 32, 72, lane), a, 0, 0, 0);
        int dcol = dc + nb + j * 16 + (lane & 15);
        float bv = b2s[dcol];
        #pragma unroll
        for (int q = 0; q < 4; ++q){
          int row = m1 + i * 16 + ((lane >> 4) << 2) + q;
          if (t0 + row < nc)
            yb[((size_t)(base + t0 + row)) * D + dcol] = f2b(a[q] + bv);
        }
      }
  }
}

// ---------------- combine: out[tok] = w0*y[g0] + w1*y[g1] ----------------
__global__ __launch_bounds__(256) void combine_kernel(
    const unsigned short* __restrict__ yb, const int* __restrict__ tsl,
    const int* __restrict__ cnt, float* __restrict__ out)
{
  int tok = blockIdx.x;
  int d0 = threadIdx.x * 8;
  const int* ts = tsl + tok * 8;
  int e0 = ts[0], p0 = ts[1]; float w0 = __int_as_float(ts[2]);
  int e1 = ts[3], p1 = ts[4]; float w1 = __int_as_float(ts[5]);
  int b0 = 0, b1s = 0;
  #pragma unroll
  for (int i = 0; i < E; ++i){
    int c = cnt[i];
    b0  += (i < e0) ? c : 0;
    b1s += (i < e1) ? c : 0;
  }
  bf16x8 y0 = *reinterpret_cast<const bf16x8*>(&yb[((size_t)(b0 + p0)) * D + d0]);
  bf16x8 y1 = *reinterpret_cast<const bf16x8*>(&yb[((size_t)(b1s + p1)) * D + d0]);
  float o[8];
  #pragma unroll
  for (int j = 0; j < 8; ++j)
    o[j] = w0 * b2f((unsigned short)y0[j]) + w1 * b2f((unsigned short)y1[j]);
  *reinterpret_cast<float4*>(&out[(size_t)tok * D + d0])     = *reinterpret_cast<float4*>(&o[0]);
  *reinterpret_cast<float4*>(&out[(size_t)tok * D + d0 + 4]) = *reinterpret_cast<float4*>(&o[4]);
}

extern "C" void kernel_launch(void* const* d_in, const int* in_sizes, int n_in,
                              void* d_out, int out_size, void* d_ws, size_t ws_size,
                              hipStream_t stream)
{
  const float* x  = (const float*)d_in[0];
  const float* u1 = (const float*)d_in[1];
  const float* v1 = (const float*)d_in[2];
  const float* b1 = (const float*)d_in[3];
  const float* u2 = (const float*)d_in[4];
  const float* v2 = (const float*)d_in[5];
  const float* b2 = (const float*)d_in[6];
  const float* gw = (const float*)d_in[7];
  const float* gb = (const float*)d_in[8];
  float* out = (float*)d_out;

  const size_t SZ_XB  = (size_t)NTOK * D * 2;   // 16 MiB
  const size_t SZ_U1P = (size_t)E * R * D * 2;  //  2 MiB
  const size_t SZ_V1P = (size_t)E * H * R * 2;  //  8 MiB
  const size_t SZ_U2P = (size_t)E * R * H * 2;  //  8 MiB
  const size_t SZ_V2P = (size_t)E * D * R * 2;  //  2 MiB
  const size_t SZ_T1  = (size_t)E * NTOK * R * 2;
  const size_t SZ_T2  = (size_t)E * NTOK * R * 4;

  char* ws = (char*)d_ws;
  size_t o = 0;
  auto take = [&](size_t b){ void* p = ws + o; o = (o + b + 255) & ~(size_t)255; return p; };
  int* cnt = (int*)take(E * 4);
  int* lst = (int*)take((size_t)E * NTOK * 4);
  int* tsl = (int*)take((size_t)NTOK * 8 * 4);
  char* A  = (char*)take(SZ_XB + SZ_U1P + SZ_V1P + SZ_U2P);   // 34 MiB
  unsigned short* xb  = (unsigned short*)A;
  unsigned short* u1p = (unsigned short*)(A + SZ_XB);
  unsigned short* v1p = (unsigned short*)(A + SZ_XB + SZ_U1P);
  unsigned short* u2p = (unsigned short*)(A + SZ_XB + SZ_U1P + SZ_V1P);
  unsigned short* yb  = (unsigned short*)A;                   // alias: all dead by out_kernel
  unsigned short* v2p = (unsigned short*)take(SZ_V2P);
  unsigned short* T1buf = (unsigned short*)take(SZ_T1);
  float* T2acc = (float*)take(SZ_T2);

  hipMemsetAsync(cnt, 0, E * 4, stream);
  hipMemsetAsync(T2acc, 0, SZ_T2, stream);

  gate_kernel<<<NTOK / 16, 256, 0, stream>>>(x, gw, gb, cnt, lst, tsl, xb);
  pack_tr<<<dim3(1, D / 64, E), 256, 0, stream>>>(u1, u1p, D, R);   // -> [r][d]
  pack_tr<<<dim3(H / 64, 1, E), 256, 0, stream>>>(v1, v1p, R, H);   // -> [h][r]
  pack_tr<<<dim3(1, H / 64, E), 256, 0, stream>>>(u2, u2p, H, R);   // -> [r][h]
  pack_tr<<<dim3(D / 64, 1, E), 256, 0, stream>>>(v2, v2p, R, D);   // -> [d][r]

  t1_kernel<<<dim3(NTOK / 64, E), 256, 0, stream>>>(xb, u1p, cnt, lst, T1buf);
  mid_kernel<<<dim3(NTOK / 64, HSPLIT, E), 512, 0, stream>>>(T1buf, v1p, u2p, b1, cnt, T2acc);
  out_kernel<<<dim3(NTOK / 64, E), 512, 0, stream>>>(T2acc, v2p, b2, cnt, yb);
  combine_kernel<<<NTOK, 256, 0, stream>>>(yb, tsl, cnt, out);
}

// Round 7
// 309.809 us; speedup vs baseline: 2.0126x; 1.1845x over previous
//
#include <hip/hip_runtime.h>
#include <hip/hip_bf16.h>

#define E 8
#define D 2048
#define H 8192
#define R 64
#define NTOK 4096
#define HSPLIT 4
#define HPER (H / HSPLIT)   // 2048

typedef __attribute__((ext_vector_type(8))) short bf16x8;
typedef __attribute__((ext_vector_type(4))) float f32x4;

__device__ __forceinline__ unsigned short f2b(float f){
  union { __hip_bfloat16 h; unsigned short u; } cv;
  cv.h = __float2bfloat16(f);
  return cv.u;
}
__device__ __forceinline__ float b2f(unsigned short u){
  union { unsigned int i; float f; } cv; cv.i = ((unsigned int)u) << 16; return cv.f;
}

// MFMA 16x16x32 fragment from [row][k] LDS tile (k in 16B-aligned chunks)
__device__ __forceinline__ bf16x8 ldfrag(const unsigned short* base, int row0, int k0,
                                         int pitch, int lane){
  return *reinterpret_cast<const bf16x8*>(base + (row0 + (lane & 15)) * pitch
                                          + k0 + ((lane >> 4) << 3));
}

// ---------------- transpose-pack: src[e][RS][CS] f32 -> dst[e][CS][RS] bf16 ----------------
__global__ __launch_bounds__(256) void pack_tr(const float* __restrict__ src,
                                               unsigned short* __restrict__ dst,
                                               int RS, int CS){
  int e = blockIdx.z;
  const float* s = src + (size_t)e * RS * CS;
  unsigned short* d = dst + (size_t)e * RS * CS;
  int c0 = blockIdx.x * 64, r0 = blockIdx.y * 64;
  int l = threadIdx.x & 63, cb = (threadIdx.x >> 6) * 16;
  int r = r0 + l;
  const float4* sp = reinterpret_cast<const float4*>(s + (size_t)r * CS + c0 + cb);
  float v[16];
  #pragma unroll
  for (int q = 0; q < 4; ++q){
    float4 t = sp[q];
    v[q*4] = t.x; v[q*4+1] = t.y; v[q*4+2] = t.z; v[q*4+3] = t.w;
  }
  #pragma unroll
  for (int j = 0; j < 16; ++j)
    d[(size_t)(c0 + cb + j) * RS + r] = f2b(v[j]);
}

// ---------------- gate v4: NO ATOMICS. logits + top2 + weights -> tsl; fused xb pack ----------------
__global__ __launch_bounds__(256) void gate_kernel(
    const float* __restrict__ x, const float* __restrict__ gw,
    const float* __restrict__ gb, int* __restrict__ tsl,
    unsigned short* __restrict__ xb)
{
  int wid  = threadIdx.x >> 6;
  int lane = threadIdx.x & 63;
  int n0 = blockIdx.x * 8 + wid * 2;      // 2 tokens per wave

  float acc[2][E];
  #pragma unroll
  for (int t = 0; t < 2; ++t)
    #pragma unroll
    for (int e = 0; e < E; ++e) acc[t][e] = 0.f;

  for (int i = 0; i < D / 256; ++i){      // 8 iters
    int dd = i * 256 + lane * 4;
    float4 xv[2];
    #pragma unroll
    for (int t = 0; t < 2; ++t){
      xv[t] = *reinterpret_cast<const float4*>(x + (size_t)(n0 + t) * D + dd);
      unsigned short o[4] = { f2b(xv[t].x), f2b(xv[t].y), f2b(xv[t].z), f2b(xv[t].w) };
      *reinterpret_cast<ushort4*>(xb + (size_t)(n0 + t) * D + dd) = *reinterpret_cast<ushort4*>(o);
    }
    #pragma unroll
    for (int e = 0; e < E; ++e){
      float4 g = *reinterpret_cast<const float4*>(gw + (size_t)e * D + dd);
      #pragma unroll
      for (int t = 0; t < 2; ++t)
        acc[t][e] += xv[t].x * g.x + xv[t].y * g.y + xv[t].z * g.z + xv[t].w * g.w;
    }
  }

  #pragma unroll
  for (int t = 0; t < 2; ++t){
    #pragma unroll
    for (int e = 0; e < E; ++e){
      float v = acc[t][e];
      for (int off = 32; off; off >>= 1) v += __shfl_xor(v, off, 64);
      acc[t][e] = v + gb[e];
    }
    if (lane == 0){
      int n = n0 + t;
      float l0 = -1e30f, l1 = -1e30f; int i0 = 0, i1 = 0;
      #pragma unroll
      for (int e = 0; e < E; ++e){
        float v = acc[t][e];
        if (v > l0){ l1 = l0; i1 = i0; l0 = v; i0 = e; }
        else if (v > l1){ l1 = v; i1 = e; }
      }
      float tt = expf(l1 - l0);
      float w0 = 1.f / (1.f + tt);
      float w1 = tt * w0;
      int* ts = tsl + n * 8;
      ts[0] = i0; ts[2] = __float_as_int(w0);
      ts[3] = i1; ts[5] = __float_as_int(w1);
    }
  }
}

// ---------------- route: wave-aggregated slot assignment (512 atomics total) ----------------
__global__ __launch_bounds__(256) void route_kernel(
    int* __restrict__ tsl, int* __restrict__ cnt, int* __restrict__ lst)
{
  int wid  = threadIdx.x >> 6;
  int lane = threadIdx.x & 63;
  int tok  = blockIdx.x * 256 + wid * 64 + lane;
  int* ts = tsl + tok * 8;
  int i0 = ts[0], i1 = ts[3];
  unsigned long long below = (1ULL << lane) - 1ULL;

  #pragma unroll
  for (int e = 0; e < E; ++e){
    unsigned long long m0 = __ballot(i0 == e);
    unsigned long long m1 = __ballot(i1 == e);
    int c0  = __popcll(m0);
    int tot = c0 + __popcll(m1);
    int base = 0;
    if (lane == 0 && tot) base = atomicAdd(&cnt[e], tot);
    base = __shfl(base, 0, 64);
    if (i0 == e){
      int p = base + __popcll(m0 & below);
      lst[e * NTOK + p] = tok;  ts[1] = p;
    }
    if (i1 == e){
      int p = base + c0 + __popcll(m1 & below);
      lst[e * NTOK + p] = tok;  ts[4] = p;
    }
  }
}

// ---------------- T1 = X_gather @ u1[e]  (64-slot tile, 256 thr) ----------------
__global__ __launch_bounds__(256) void t1_kernel(
    const unsigned short* __restrict__ xb, const unsigned short* __restrict__ u1p,
    const int* __restrict__ cnt, const int* __restrict__ lst,
    unsigned short* __restrict__ T1buf)
{
  int e = blockIdx.y;
  int nc = cnt[e];
  int t0 = blockIdx.x * 64;
  if (t0 >= nc) return;

  __shared__ int s_tok[64];
  __shared__ unsigned short Xs[64 * 136];
  __shared__ unsigned short U1s[64 * 136];
  int tid = threadIdx.x, w = tid >> 6, lane = tid & 63;

  if (tid < 64) s_tok[tid] = lst[e * NTOK + min(t0 + tid, nc - 1)];
  __syncthreads();

  int m = (w & 3) * 16;
  f32x4 z = {0.f, 0.f, 0.f, 0.f};
  f32x4 acc[4] = {z, z, z, z};

  for (int kc = 0; kc < D; kc += 128){
    __syncthreads();
    #pragma unroll
    for (int s = 0; s < 4; ++s){
      int id = tid + s * 256;
      int rr = id >> 4, c = (id & 15) * 8;
      *reinterpret_cast<bf16x8*>(&Xs[rr * 136 + c]) =
        *reinterpret_cast<const bf16x8*>(&xb[(size_t)s_tok[rr] * D + kc + c]);
      *reinterpret_cast<bf16x8*>(&U1s[rr * 136 + c]) =
        *reinterpret_cast<const bf16x8*>(&u1p[((size_t)e * R + rr) * D + kc + c]);
    }
    __syncthreads();
    #pragma unroll
    for (int j = 0; j < 4; ++j)
      #pragma unroll
      for (int ks = 0; ks < 4; ++ks)
        acc[j] = __builtin_amdgcn_mfma_f32_16x16x32_bf16(
            ldfrag(Xs, m, ks * 32, 136, lane),
            ldfrag(U1s, j * 16, ks * 32, 136, lane), acc[j], 0, 0, 0);
  }
  #pragma unroll
  for (int j = 0; j < 4; ++j){
    int col = j * 16 + (lane & 15);
    #pragma unroll
    for (int q = 0; q < 4; ++q){
      int row = m + ((lane >> 4) << 2) + q;
      T1buf[((size_t)e * NTOK + t0 + row) * R + col] = f2b(acc[j][q]);
    }
  }
}

// ---------------- mid: T2 += relu(T1 @ v1 + b1) @ u2  (64 slots x H/4 per block) ----------------
__global__ __launch_bounds__(512, 4) void mid_kernel(
    const unsigned short* __restrict__ T1buf, const unsigned short* __restrict__ v1p,
    const unsigned short* __restrict__ u2p, const float* __restrict__ b1,
    const int* __restrict__ cnt, float* __restrict__ T2acc)
{
  int e = blockIdx.z;
  int nc = cnt[e];
  int t0 = blockIdx.x * 64;
  if (t0 >= nc) return;
  int hc0 = blockIdx.y * HPER;

  __shared__ unsigned short T1s[64 * 72];
  __shared__ unsigned short v1s[128 * 72];
  __shared__ unsigned short u2s[64 * 136];
  __shared__ unsigned short Hs[64 * 136];
  __shared__ float b1s[HPER];

  int tid = threadIdx.x, w = tid >> 6, lane = tid & 63;

  { int rr = tid >> 3, c = (tid & 7) * 8;
    *reinterpret_cast<bf16x8*>(&T1s[rr * 72 + c]) =
      *reinterpret_cast<const bf16x8*>(&T1buf[((size_t)e * NTOK + t0 + rr) * R + c]); }
  for (int i = tid; i < HPER; i += 512) b1s[i] = b1[(size_t)e * H + hc0 + i];

  int m1 = (w & 1) * 32, n1 = (w >> 1) * 32;   // B1: 64x128
  int m2 = (w & 3) * 16, r2 = (w >> 2) * 32;   // B2: 64x64
  f32x4 z = {0.f, 0.f, 0.f, 0.f};
  f32x4 acc[2] = {z, z};

  // register prefetch of subchunk 0 (T14 pattern)
  bf16x8 pv[2], pu[2];
  #pragma unroll
  for (int s = 0; s < 2; ++s){
    int id = tid + s * 512;
    pv[s] = *reinterpret_cast<const bf16x8*>(&v1p[((size_t)e * H + hc0 + (id >> 3)) * R + (id & 7) * 8]);
    pu[s] = *reinterpret_cast<const bf16x8*>(&u2p[((size_t)e * R + (id >> 4)) * H + hc0 + (id & 15) * 8]);
  }

  for (int hs = 0; hs < HPER; hs += 128){
    __syncthreads();                            // prev B2 done reading v1s/u2s
    #pragma unroll
    for (int s = 0; s < 2; ++s){
      int id = tid + s * 512;
      *reinterpret_cast<bf16x8*>(&v1s[(id >> 3) * 72 + (id & 7) * 8]) = pv[s];
      *reinterpret_cast<bf16x8*>(&u2s[(id >> 4) * 136 + (id & 15) * 8]) = pu[s];
    }
    __syncthreads();
    // B1: Hs = relu(T1s @ v1s^T + b1)
    #pragma unroll
    for (int i = 0; i < 2; ++i)
      #pragma unroll
      for (int j = 0; j < 2; ++j){
        f32x4 a = z;
        #pragma unroll
        for (int ks = 0; ks < 2; ++ks)
          a = __builtin_amdgcn_mfma_f32_16x16x32_bf16(
              ldfrag(T1s, m1 + i * 16, ks * 32, 72, lane),
              ldfrag(v1s, n1 + j * 16, ks * 32, 72, lane), a, 0, 0, 0);
        int hcol = n1 + j * 16 + (lane & 15);
        float bv = b1s[hs + hcol];
        #pragma unroll
        for (int q = 0; q < 4; ++q){
          float vv = a[q] + bv;
          Hs[(m1 + i * 16 + ((lane >> 4) << 2) + q) * 136 + hcol] = f2b(vv > 0.f ? vv : 0.f);
        }
      }
    // prefetch next subchunk into regs (overlaps barrier + B2)
    int hn = (hs + 128 < HPER) ? hs + 128 : 0;
    #pragma unroll
    for (int s = 0; s < 2; ++s){
      int id = tid + s * 512;
      pv[s] = *reinterpret_cast<const bf16x8*>(&v1p[((size_t)e * H + hc0 + hn + (id >> 3)) * R + (id & 7) * 8]);
      pu[s] = *reinterpret_cast<const bf16x8*>(&u2p[((size_t)e * R + (id >> 4)) * H + hc0 + hn + (id & 15) * 8]);
    }
    __syncthreads();                            // Hs ready
    // B2: acc += Hs @ u2s^T
    #pragma unroll
    for (int j = 0; j < 2; ++j)
      #pragma unroll
      for (int ks = 0; ks < 4; ++ks)
        acc[j] = __builtin_amdgcn_mfma_f32_16x16x32_bf16(
            ldfrag(Hs, m2, ks * 32, 136, lane),
            ldfrag(u2s, r2 + j * 16, ks * 32, 136, lane), acc[j], 0, 0, 0);
  }
  #pragma unroll
  for (int j = 0; j < 2; ++j){
    int col = r2 + j * 16 + (lane & 15);
    #pragma unroll
    for (int q = 0; q < 4; ++q){
      int row = m2 + ((lane >> 4) << 2) + q;
      atomicAdd(&T2acc[((size_t)e * NTOK + t0 + row) * R + col], acc[j][q]);
    }
  }
}

// ---------------- out: y[slot] = T2 @ v2[e] + b2  -> compact bf16 yb ----------------
__global__ __launch_bounds__(512, 4) void out_kernel(
    const float* __restrict__ T2acc, const unsigned short* __restrict__ v2p,
    const float* __restrict__ b2, const int* __restrict__ cnt,
    unsigned short* __restrict__ yb)
{
  int e = blockIdx.y;
  int nc = cnt[e];
  int t0 = blockIdx.x * 64;
  if (t0 >= nc) return;
  int base = 0;
  #pragma unroll
  for (int i = 0; i < E; ++i) base += (i < e) ? cnt[i] : 0;

  __shared__ unsigned short T2s[64 * 72];
  __shared__ unsigned short v2s[256 * 72];
  __shared__ float b2s[D];
  int tid = threadIdx.x, w = tid >> 6, lane = tid & 63;

  { int rr = tid >> 3, c = (tid & 7) * 8;
    const float* src = &T2acc[((size_t)e * NTOK + t0 + rr) * R + c];
    float4 a = *reinterpret_cast<const float4*>(src);
    float4 b = *reinterpret_cast<const float4*>(src + 4);
    unsigned short o[8] = { f2b(a.x), f2b(a.y), f2b(a.z), f2b(a.w),
                            f2b(b.x), f2b(b.y), f2b(b.z), f2b(b.w) };
    *reinterpret_cast<bf16x8*>(&T2s[rr * 72 + c]) = *reinterpret_cast<bf16x8*>(o); }
  for (int i = tid; i < D; i += 512) b2s[i] = b2[(size_t)e * D + i];

  int m1 = (w & 1) * 32, nb = (w >> 1) * 64;
  f32x4 z = {0.f, 0.f, 0.f, 0.f};

  for (int dc = 0; dc < D; dc += 256){
    __syncthreads();
    #pragma unroll
    for (int s = 0; s < 4; ++s){
      int id = tid + s * 512;
      int rr = id >> 3, c = (id & 7) * 8;
      *reinterpret_cast<bf16x8*>(&v2s[rr * 72 + c]) =
        *reinterpret_cast<const bf16x8*>(&v2p[((size_t)e * D + dc + rr) * R + c]);
    }
    __syncthreads();
    #pragma unroll
    for (int i = 0; i < 2; ++i)
      #pragma unroll
      for (int j = 0; j < 4; ++j){
        f32x4 a = z;
        #pragma unroll
        for (int ks = 0; ks < 2; ++ks)
          a = __builtin_amdgcn_mfma_f32_16x16x32_bf16(
              ldfrag(T2s, m1 + i * 16, ks * 32, 72, lane),
              ldfrag(v2s, nb + j * 16, ks * 32, 72, lane), a, 0, 0, 0);
        int dcol = dc + nb + j * 16 + (lane & 15);
        float bv = b2s[dcol];
        #pragma unroll
        for (int q = 0; q < 4; ++q){
          int row = m1 + i * 16 + ((lane >> 4) << 2) + q;
          if (t0 + row < nc)
            yb[((size_t)(base + t0 + row)) * D + dcol] = f2b(a[q] + bv);
        }
      }
  }
}

// ---------------- combine: out[tok] = w0*y[g0] + w1*y[g1] ----------------
__global__ __launch_bounds__(256) void combine_kernel(
    const unsigned short* __restrict__ yb, const int* __restrict__ tsl,
    const int* __restrict__ cnt, float* __restrict__ out)
{
  int tok = blockIdx.x;
  int d0 = threadIdx.x * 8;
  const int* ts = tsl + tok * 8;
  int e0 = ts[0], p0 = ts[1]; float w0 = __int_as_float(ts[2]);
  int e1 = ts[3], p1 = ts[4]; float w1 = __int_as_float(ts[5]);
  int b0 = 0, b1s = 0;
  #pragma unroll
  for (int i = 0; i < E; ++i){
    int c = cnt[i];
    b0  += (i < e0) ? c : 0;
    b1s += (i < e1) ? c : 0;
  }
  bf16x8 y0 = *reinterpret_cast<const bf16x8*>(&yb[((size_t)(b0 + p0)) * D + d0]);
  bf16x8 y1 = *reinterpret_cast<const bf16x8*>(&yb[((size_t)(b1s + p1)) * D + d0]);
  float o[8];
  #pragma unroll
  for (int j = 0; j < 8; ++j)
    o[j] = w0 * b2f((unsigned short)y0[j]) + w1 * b2f((unsigned short)y1[j]);
  *reinterpret_cast<float4*>(&out[(size_t)tok * D + d0])     = *reinterpret_cast<float4*>(&o[0]);
  *reinterpret_cast<float4*>(&out[(size_t)tok * D + d0 + 4]) = *reinterpret_cast<float4*>(&o[4]);
}

extern "C" void kernel_launch(void* const* d_in, const int* in_sizes, int n_in,
                              void* d_out, int out_size, void* d_ws, size_t ws_size,
                              hipStream_t stream)
{
  const float* x  = (const float*)d_in[0];
  const float* u1 = (const float*)d_in[1];
  const float* v1 = (const float*)d_in[2];
  const float* b1 = (const float*)d_in[3];
  const float* u2 = (const float*)d_in[4];
  const float* v2 = (const float*)d_in[5];
  const float* b2 = (const float*)d_in[6];
  const float* gw = (const float*)d_in[7];
  const float* gb = (const float*)d_in[8];
  float* out = (float*)d_out;

  const size_t SZ_XB  = (size_t)NTOK * D * 2;   // 16 MiB
  const size_t SZ_U1P = (size_t)E * R * D * 2;  //  2 MiB
  const size_t SZ_V1P = (size_t)E * H * R * 2;  //  8 MiB
  const size_t SZ_U2P = (size_t)E * R * H * 2;  //  8 MiB
  const size_t SZ_V2P = (size_t)E * D * R * 2;  //  2 MiB
  const size_t SZ_T1  = (size_t)E * NTOK * R * 2;
  const size_t SZ_T2  = (size_t)E * NTOK * R * 4;

  char* ws = (char*)d_ws;
  size_t o = 0;
  auto take = [&](size_t b){ void* p = ws + o; o = (o + b + 255) & ~(size_t)255; return p; };
  int* cnt = (int*)take(E * 4);
  int* lst = (int*)take((size_t)E * NTOK * 4);
  int* tsl = (int*)take((size_t)NTOK * 8 * 4);
  char* A  = (char*)take(SZ_XB + SZ_U1P + SZ_V1P + SZ_U2P);   // 34 MiB
  unsigned short* xb  = (unsigned short*)A;
  unsigned short* u1p = (unsigned short*)(A + SZ_XB);
  unsigned short* v1p = (unsigned short*)(A + SZ_XB + SZ_U1P);
  unsigned short* u2p = (unsigned short*)(A + SZ_XB + SZ_U1P + SZ_V1P);
  unsigned short* yb  = (unsigned short*)A;                   // alias: all dead by out_kernel
  unsigned short* v2p = (unsigned short*)take(SZ_V2P);
  unsigned short* T1buf = (unsigned short*)take(SZ_T1);
  float* T2acc = (float*)take(SZ_T2);

  hipMemsetAsync(cnt, 0, E * 4, stream);
  hipMemsetAsync(T2acc, 0, SZ_T2, stream);

  gate_kernel<<<NTOK / 8, 256, 0, stream>>>(x, gw, gb, tsl, xb);
  route_kernel<<<NTOK / 256, 256, 0, stream>>>(tsl, cnt, lst);
  pack_tr<<<dim3(1, D / 64, E), 256, 0, stream>>>(u1, u1p, D, R);   // -> [r][d]
  pack_tr<<<dim3(H / 64, 1, E), 256, 0, stream>>>(v1, v1p, R, H);   // -> [h][r]
  pack_tr<<<dim3(1, H / 64, E), 256, 0, stream>>>(u2, u2p, H, R);   // -> [r][h]
  pack_tr<<<dim3(D / 64, 1, E), 256, 0, stream>>>(v2, v2p, R, D);   // -> [d][r]

  t1_kernel<<<dim3(NTOK / 64, E), 256, 0, stream>>>(xb, u1p, cnt, lst, T1buf);
  mid_kernel<<<dim3(NTOK / 64, HSPLIT, E), 512, 0, stream>>>(T1buf, v1p, u2p, b1, cnt, T2acc);
  out_kernel<<<dim3(NTOK / 64, E), 512, 0, stream>>>(T2acc, v2p, b2, cnt, yb);
  combine_kernel<<<NTOK, 256, 0, stream>>>(yb, tsl, cnt, out);
}